// Round 18
// baseline (250.640 us; speedup 1.0000x reference)
//
#include <hip/hip_runtime.h>
#include <math.h>
#include <float.h>

// DeepSeek V3 router, round 18.
// Pipe-audit conclusion (R9-R17): A-fragment LDS reads are 4x wave-redundant
// -> LDS ceiling ~41% MfmaUtil; measured 26-28% = ceiling x ~68% sync
// efficiency. Register-infeasible to change the ratio (R15/R16). This round
// attacks the 68%: R9 was GRID-capped at 2 blocks/CU (splitK=4 -> 512).
// splitK=6 -> grid 768 = exactly 3 blocks/CU (no tail), uneven K slices
// (38,38,37,37,37,37 tiles), launch_bounds(256,3) (R9 used 156 unified regs,
// fits the ~170 3-wave budget). Everything else VERBATIM validated R9:
// 64Mx256N block, 4 waves, wave-tile 64x64, A swizzled LDS dbuf
// (conflict-free), B global->reg fragment-packed L2-resident planes.
// Numerics (validated R7-R17): pass1 a0*b0; b0*=S5; a1*=S6; pass2 a1*b0s;
// a0*=S5; pass3 a0s*b3; a0=fp16(x), a1=fp16(res_x*2048), b0=fp16(256w),
// b3=fp16(res_w256*32); logit = acc/256.

#define TDIM 8192
#define DDIM 7168
#define EDIM 256
#define KT   (DDIM / 32)   // 224 k-tiles of 32
#define SPLITK 6

typedef _Float16 h8 __attribute__((ext_vector_type(8)));
typedef float  f16v __attribute__((ext_vector_type(16)));

// ---------------- K1: W -> 32x32x16-fragment-packed fp16 planes ------------
// (verbatim R9, validated) Offset(halfs) = (((p*8+cf)*KT+ktl)*2+kf)*512
// + lane*8, lane = (e&31) + 32*((k>>3)&1).
__global__ __launch_bounds__(256)
void convert_w(const float* __restrict__ W, _Float16* __restrict__ Bp)
{
    __shared__ _Float16 l0[64][80];
    __shared__ _Float16 l1[64][80];
    const int t = threadIdx.x;
    const int kt = blockIdx.x * 64;
    const int et = blockIdx.y * 64;
#pragma unroll
    for (int i = 0; i < 16; ++i) {
        const int kr = (t >> 6) * 16 + i;
        const int ec = t & 63;
        const float w = W[(size_t)(kt + kr) * EDIM + et + ec] * 256.f;
        const _Float16 h0 = (_Float16)w;
        const _Float16 h1 = (_Float16)((w - (float)h0) * 32.f);
        l0[ec][kr] = h0;
        l1[ec][kr] = h1;
    }
    __syncthreads();
#pragma unroll
    for (int j = 0; j < 2; ++j) {
        const int er = t >> 2;
        const int kc = ((t & 3) + 4 * j) * 8;
        const int e  = et + er;
        const int k  = kt + kc;
        const int cf   = e >> 5;
        const int lane = (e & 31) + 32 * ((k >> 3) & 1);
        const int kf   = (k >> 4) & 1;
        const int ktl  = k >> 5;
        const uint4 v0 = *(const uint4*)&l0[er][kc];
        const uint4 v1 = *(const uint4*)&l1[er][kc];
        const size_t o0 = (((size_t)(0 * 8 + cf) * KT + ktl) * 2 + kf) * 512 + lane * 8;
        const size_t o1 = (((size_t)(1 * 8 + cf) * KT + ktl) * 2 + kf) * 512 + lane * 8;
        *(uint4*)&Bp[o0] = v0;
        *(uint4*)&Bp[o1] = v1;
    }
}

// ---- K2: 32x32x16 split-fp16 GEMM (R9 verbatim) + splitK=6, 3 blocks/CU ---
__global__ __launch_bounds__(256, 3)
void gemm_mfma(const float* __restrict__ X,
               const _Float16* __restrict__ Bp,
               float* __restrict__ P)
{
    __shared__ _Float16 sA[2][2][64][32];   // 16 KB: [buf][plane][row][halfs]

    const int t    = threadIdx.x;
    const int lane = t & 63;
    const int w    = t >> 6;                // wave 0..3 -> cols w*64..+63

    // XCD-chunked remap: consecutive logical ids (sharing mb / X rows) on one XCD
    const int cpx = gridDim.x >> 3;         // 96
    const int L   = (blockIdx.x & 7) * cpx + (blockIdx.x >> 3);
    const int ks  = L % SPLITK;
    const int mb  = L / SPLITK;
    const int m0  = mb * 64;
    // uneven K slices: tiles 38,38,37,37,37,37 (sum 224)
    const int ktg0 = ks * 37 + (ks < 2 ? ks : 2);
    const int nt   = 37 + (ks < 2 ? 1 : 0);
    const int kbeg = ktg0 * 32;

    f16v acc[2][2];
#pragma unroll
    for (int m = 0; m < 2; ++m)
#pragma unroll
        for (int n = 0; n < 2; ++n) acc[m][n] = (f16v)0.f;

    // A staging: thread -> row t>>2 (0..63), granule t&3 (8 floats)
    const int rowA  = t >> 2;
    const int gA    = t & 3;
    const float* xg = X + (size_t)(m0 + rowA) * DDIM + kbeg + gA * 8;
    const int slotA = (gA ^ ((rowA >> 2) & 3)) * 8;   // validated swizzle

    const _Float16* bbase = Bp + lane * 8;

    float4 va0, va1;

#define LOADA(kb)                                                             \
    {                                                                         \
        va0 = *(const float4*)(xg + (kb));                                    \
        va1 = *(const float4*)(xg + (kb) + 4);                                \
    }

#define WRITEA(buf)                                                           \
    {                                                                         \
        h8 p0, p1;                                                            \
        const float xv[8] = {va0.x, va0.y, va0.z, va0.w,                      \
                             va1.x, va1.y, va1.z, va1.w};                     \
        _Pragma("unroll")                                                     \
        for (int q = 0; q < 8; ++q) {                                         \
            const _Float16 h0 = (_Float16)xv[q];                              \
            p0[q] = h0;                                                       \
            p1[q] = (_Float16)((xv[q] - (float)h0) * 2048.f);                 \
        }                                                                     \
        *(h8*)&sA[buf][0][rowA][slotA] = p0;                                  \
        *(h8*)&sA[buf][1][rowA][slotA] = p1;                                  \
    }

    // RB[p][n][kf]
#define BLOAD(RB, TI)                                                         \
    {                                                                         \
        _Pragma("unroll")                                                     \
        for (int p = 0; p < 2; ++p)                                           \
        _Pragma("unroll")                                                     \
        for (int n = 0; n < 2; ++n)                                           \
        _Pragma("unroll")                                                     \
        for (int kf = 0; kf < 2; ++kf)                                        \
            RB[p][n][kf] = *(const h8*)(bbase +                               \
                (((size_t)(p * 8 + w * 2 + n) * KT + ktg0 + (TI)) * 2 + kf) * 512); \
    }

#define AREAD(CUR)                                                            \
    {                                                                         \
        _Pragma("unroll")                                                     \
        for (int m = 0; m < 2; ++m)                                           \
        _Pragma("unroll")                                                     \
        for (int kf = 0; kf < 2; ++kf) {                                      \
            const int rr = m * 32 + (lane & 31);                              \
            const int sl = (((lane >> 5) + 2 * kf) ^ ((rr >> 2) & 3)) * 8;    \
            a0[m][kf] = *(const h8*)&sA[CUR][0][rr][sl];                      \
            a1[m][kf] = *(const h8*)&sA[CUR][1][rr][sl];                      \
        }                                                                     \
    }

#define MFMA3(RB)                                                             \
    {                                                                         \
        __builtin_amdgcn_s_setprio(1);                                        \
        _Pragma("unroll")                                                     \
        for (int m = 0; m < 2; ++m)                                           \
        _Pragma("unroll")                                                     \
        for (int n = 0; n < 2; ++n)                                           \
        _Pragma("unroll")                                                     \
        for (int kf = 0; kf < 2; ++kf)                                        \
            acc[m][n] = __builtin_amdgcn_mfma_f32_32x32x16_f16(               \
                a0[m][kf], RB[0][n][kf], acc[m][n], 0, 0, 0);                 \
        _Pragma("unroll")                                                     \
        for (int n = 0; n < 2; ++n)                                           \
        _Pragma("unroll")                                                     \
        for (int kf = 0; kf < 2; ++kf)                                        \
        _Pragma("unroll")                                                     \
        for (int q = 0; q < 8; ++q) RB[0][n][kf][q] *= S5;                    \
        _Pragma("unroll")                                                     \
        for (int m = 0; m < 2; ++m)                                           \
        _Pragma("unroll")                                                     \
        for (int kf = 0; kf < 2; ++kf)                                        \
        _Pragma("unroll")                                                     \
        for (int q = 0; q < 8; ++q) a1[m][kf][q] *= S6;                       \
        _Pragma("unroll")                                                     \
        for (int m = 0; m < 2; ++m)                                           \
        _Pragma("unroll")                                                     \
        for (int n = 0; n < 2; ++n)                                           \
        _Pragma("unroll")                                                     \
        for (int kf = 0; kf < 2; ++kf)                                        \
            acc[m][n] = __builtin_amdgcn_mfma_f32_32x32x16_f16(               \
                a1[m][kf], RB[0][n][kf], acc[m][n], 0, 0, 0);                 \
        _Pragma("unroll")                                                     \
        for (int m = 0; m < 2; ++m)                                           \
        _Pragma("unroll")                                                     \
        for (int kf = 0; kf < 2; ++kf)                                        \
        _Pragma("unroll")                                                     \
        for (int q = 0; q < 8; ++q) a0[m][kf][q] *= S5;                       \
        _Pragma("unroll")                                                     \
        for (int m = 0; m < 2; ++m)                                           \
        _Pragma("unroll")                                                     \
        for (int n = 0; n < 2; ++n)                                           \
        _Pragma("unroll")                                                     \
        for (int kf = 0; kf < 2; ++kf)                                        \
            acc[m][n] = __builtin_amdgcn_mfma_f32_32x32x16_f16(               \
                a0[m][kf], RB[1][n][kf], acc[m][n], 0, 0, 0);                 \
        __builtin_amdgcn_s_setprio(0);                                        \
    }

    const _Float16 S5 = (_Float16)0.03125f;     // 2^-5
    const _Float16 S6 = (_Float16)0.015625f;    // 2^-6

    h8 bE[2][2][2], bO[2][2][2];

    // ---- prologue: A(0)->buf0; B(0)->E ----
    LOADA(0);
    BLOAD(bE, 0);
    WRITEA(0);
    asm volatile("s_waitcnt lgkmcnt(0)" ::: "memory");
    __builtin_amdgcn_s_barrier();

    for (int ti = 0; ti < nt; ti += 2) {
        {   // even: tile ti from sA[0], bE
            h8 a0[2][2], a1[2][2];
            const bool hn = (ti + 1) < nt;
            if (hn) { LOADA((ti + 1) * 32); BLOAD(bO, ti + 1); }
            AREAD(0);
            MFMA3(bE);
            if (hn) WRITEA(1);
            asm volatile("s_waitcnt lgkmcnt(0)" ::: "memory");
            __builtin_amdgcn_s_barrier();
        }
        {   // odd: tile ti+1 from sA[1], bO
            h8 a0[2][2], a1[2][2];
            const bool hn = (ti + 2) < nt;
            if (hn) { LOADA((ti + 2) * 32); BLOAD(bE, ti + 2); }
            if (ti + 1 < nt) {
                AREAD(1);
                MFMA3(bO);
            }
            if (hn) WRITEA(0);
            asm volatile("s_waitcnt lgkmcnt(0)" ::: "memory");
            __builtin_amdgcn_s_barrier();
        }
    }

    // epilogue: logit = acc/256; C/D col=lane&31, row=(r&3)+8*(r>>2)+4*(lane>>5)
    const float s0 = 1.f / 256.f;
#pragma unroll
    for (int m = 0; m < 2; ++m)
#pragma unroll
        for (int n = 0; n < 2; ++n)
#pragma unroll
            for (int r = 0; r < 16; ++r) {
                const int row = (r & 3) + 8 * (r >> 2) + 4 * (lane >> 5);
                const int gr  = m0 + m * 32 + row;
                const int gc  = w * 64 + n * 32 + (lane & 31);
                P[((size_t)ks * TDIM + gr) * EDIM + gc] = acc[m][n][r] * s0;
            }
}

// ---------------- K3: reduce + sigmoid + grouped top-k route ----------------
__global__ __launch_bounds__(256, 4)
void route_kernel(const float* __restrict__ P,
                  const float* __restrict__ B,
                  float* __restrict__ out,
                  int splitK)
{
    const int t    = threadIdx.x;
    const int lane = t & 63;
    const int wid  = t >> 6;
    const int tok0 = blockIdx.x * 32 + wid * 8;

    const float4 bv4 = *(const float4*)&B[lane * 4];
    const float bb[4] = {bv4.x, bv4.y, bv4.z, bv4.w};
    const int g = lane >> 3;

#pragma unroll
    for (int i = 0; i < 8; ++i) {
        const int tok = tok0 + i;
        float a[4] = {0.f, 0.f, 0.f, 0.f};
        for (int ksl = 0; ksl < splitK; ++ksl) {
            const float4 pv =
                *(const float4*)&P[((size_t)ksl * TDIM + tok) * EDIM + lane * 4];
            a[0] += pv.x; a[1] += pv.y; a[2] += pv.z; a[3] += pv.w;
        }
        float v[4], s[4];
#pragma unroll
        for (int jq = 0; jq < 4; ++jq) {
            v[jq] = 1.f / (1.f + expf(-a[jq]));
            s[jq] = v[jq] + bb[jq];
        }
        float t1 = s[0], t2 = -FLT_MAX;
#pragma unroll
        for (int jq = 1; jq < 4; ++jq) {
            if (s[jq] > t1) { t2 = t1; t1 = s[jq]; }
            else if (s[jq] > t2) t2 = s[jq];
        }
#pragma unroll
        for (int d = 1; d < 8; d <<= 1) {
            float o1 = __shfl_xor(t1, d);
            float o2 = __shfl_xor(t2, d);
            float n1 = fmaxf(t1, o1);
            float n2 = fmaxf(fminf(t1, o1), fmaxf(t2, o2));
            t1 = n1; t2 = n2;
        }
        const float gsc = t1 + t2;
        float gs[8];
#pragma unroll
        for (int q = 0; q < 8; ++q) gs[q] = __shfl(gsc, q * 8);
        int gmask = 0;
#pragma unroll
        for (int it = 0; it < 4; ++it) {
            float bvv = -FLT_MAX; int bg = 0;
#pragma unroll
            for (int q = 0; q < 8; ++q) {
                const bool avail = ((gmask >> q) & 1) == 0;
                if (avail && gs[q] > bvv) { bvv = gs[q]; bg = q; }
            }
            gmask |= (1 << bg);
        }
        if (((gmask >> g) & 1) == 0) { s[0] = 0.f; s[1] = 0.f; s[2] = 0.f; s[3] = 0.f; }

        float wk[8]; int ik[8]; float wsum = 0.f;
#pragma unroll
        for (int it = 0; it < 8; ++it) {
            float bvv = s[0]; int bi = lane * 4; float bs = v[0];
#pragma unroll
            for (int jq = 1; jq < 4; ++jq)
                if (s[jq] > bvv) { bvv = s[jq]; bi = lane * 4 + jq; bs = v[jq]; }
#pragma unroll
            for (int d = 1; d < 64; d <<= 1) {
                float ov = __shfl_xor(bvv, d);
                int   oi = __shfl_xor(bi, d);
                float os = __shfl_xor(bs, d);
                if (ov > bvv || (ov == bvv && oi < bi)) { bvv = ov; bi = oi; bs = os; }
            }
            wk[it] = bs; ik[it] = bi; wsum += bs;
#pragma unroll
            for (int jq = 0; jq < 4; ++jq)
                if (bi == lane * 4 + jq) s[jq] = -FLT_MAX;
        }
        const float den = wsum + 1e-20f;
        if (lane == 0) {
#pragma unroll
            for (int q = 0; q < 8; ++q) {
                out[(size_t)tok * 8 + q] = wk[q] / den * 2.5f;
                out[(size_t)TDIM * 8 + (size_t)tok * 8 + q] = (float)ik[q];
            }
        }
    }
}

extern "C" void kernel_launch(void* const* d_in, const int* in_sizes, int n_in,
                              void* d_out, int out_size, void* d_ws, size_t ws_size,
                              hipStream_t stream)
{
    (void)in_sizes; (void)n_in; (void)out_size; (void)ws_size;
    const float* x    = (const float*)d_in[0];
    const float* kern = (const float*)d_in[1];
    const float* bias = (const float*)d_in[2];
    float* out = (float*)d_out;

    float* P = (float*)d_ws;                                     // 6x8MB = 50.3MB
    _Float16* Bp = (_Float16*)((char*)d_ws +
                               (size_t)SPLITK * TDIM * EDIM * 4);

    convert_w<<<dim3(DDIM / 64, EDIM / 64), 256, 0, stream>>>(kern, Bp);
    gemm_mfma<<<(TDIM / 64) * SPLITK, 256, 0, stream>>>(x, Bp, P);
    route_kernel<<<TDIM / 32, 256, 0, stream>>>(P, bias, out, SPLITK);
}

// Round 19
// 185.534 us; speedup vs baseline: 1.3509x; 1.3509x over previous
//
#include <hip/hip_runtime.h>
#include <math.h>
#include <float.h>

// DeepSeek V3 router, round 19.
// R18 failed on two self-inflicted bugs: launch_bounds(256,3) register cap
// (-> 210MB scratch) and an XCD remap that cycled ks within an XCD
// (-> B L2 locality destroyed, FETCH +88MB). R19 = validated R9 kernel with
// ONE clean delta: splitK=6 -> grid 768 = exactly 3 blocks/CU.
//  - launch_bounds stays (256,2): it is a floor, not a cap; R9's 156 unified
//    regs <= 170 (3 waves/SIMD budget) so hardware runs 3 blocks/CU.
//  - chunked ks mapping: L = (bid&7)*96 + (bid>>3); ks = L/128, mb = L%128.
//    Consecutive L (same XCD) share one ks -> B slice (1.2MB) L2-resident,
//    <=2 slices per XCD; contiguous mb -> X-row locality.
//  - uneven K slices 38,38,37,37,37,37 (sum 224); odd-nt guards in the loop.
// Numerics (validated R7-R18): pass1 a0*b0; b0*=S5; a1*=S6; pass2 a1*b0s;
// a0*=S5; pass3 a0s*b3; a0=fp16(x), a1=fp16(res_x*2048), b0=fp16(256w),
// b3=fp16(res_w256*32); logit = acc/256.

#define TDIM 8192
#define DDIM 7168
#define EDIM 256
#define KT   (DDIM / 32)   // 224 k-tiles of 32
#define SPLITK 6

typedef _Float16 h8 __attribute__((ext_vector_type(8)));
typedef float  f16v __attribute__((ext_vector_type(16)));

// ---------------- K1: W -> 32x32x16-fragment-packed fp16 planes ------------
// (verbatim R9, validated) Offset(halfs) = (((p*8+cf)*KT+ktl)*2+kf)*512
// + lane*8, lane = (e&31) + 32*((k>>3)&1).
__global__ __launch_bounds__(256)
void convert_w(const float* __restrict__ W, _Float16* __restrict__ Bp)
{
    __shared__ _Float16 l0[64][80];
    __shared__ _Float16 l1[64][80];
    const int t = threadIdx.x;
    const int kt = blockIdx.x * 64;
    const int et = blockIdx.y * 64;
#pragma unroll
    for (int i = 0; i < 16; ++i) {
        const int kr = (t >> 6) * 16 + i;
        const int ec = t & 63;
        const float w = W[(size_t)(kt + kr) * EDIM + et + ec] * 256.f;
        const _Float16 h0 = (_Float16)w;
        const _Float16 h1 = (_Float16)((w - (float)h0) * 32.f);
        l0[ec][kr] = h0;
        l1[ec][kr] = h1;
    }
    __syncthreads();
#pragma unroll
    for (int j = 0; j < 2; ++j) {
        const int er = t >> 2;
        const int kc = ((t & 3) + 4 * j) * 8;
        const int e  = et + er;
        const int k  = kt + kc;
        const int cf   = e >> 5;
        const int lane = (e & 31) + 32 * ((k >> 3) & 1);
        const int kf   = (k >> 4) & 1;
        const int ktl  = k >> 5;
        const uint4 v0 = *(const uint4*)&l0[er][kc];
        const uint4 v1 = *(const uint4*)&l1[er][kc];
        const size_t o0 = (((size_t)(0 * 8 + cf) * KT + ktl) * 2 + kf) * 512 + lane * 8;
        const size_t o1 = (((size_t)(1 * 8 + cf) * KT + ktl) * 2 + kf) * 512 + lane * 8;
        *(uint4*)&Bp[o0] = v0;
        *(uint4*)&Bp[o1] = v1;
    }
}

// ---- K2: 32x32x16 split-fp16 GEMM (R9 verbatim), splitK=6 / 3 blocks/CU ---
__global__ __launch_bounds__(256, 2)
void gemm_mfma(const float* __restrict__ X,
               const _Float16* __restrict__ Bp,
               float* __restrict__ P)
{
    __shared__ _Float16 sA[2][2][64][32];   // 16 KB: [buf][plane][row][halfs]

    const int t    = threadIdx.x;
    const int lane = t & 63;
    const int w    = t >> 6;                // wave 0..3 -> cols w*64..+63

    // chunked remap: same-XCD blocks get consecutive L -> one ks, contiguous mb
    const int cpx = gridDim.x >> 3;         // 96
    const int L   = (blockIdx.x & 7) * cpx + (blockIdx.x >> 3);
    const int ks  = L / 128;                // 0..5 (chunk of 128 mb per ks)
    const int mb  = L - ks * 128;
    const int m0  = mb * 64;
    // uneven K slices: tiles 38,38,37,37,37,37 (sum 224)
    const int ktg0 = ks * 37 + (ks < 2 ? ks : 2);
    const int nt   = 37 + (ks < 2 ? 1 : 0);
    const int kbeg = ktg0 * 32;

    f16v acc[2][2];
#pragma unroll
    for (int m = 0; m < 2; ++m)
#pragma unroll
        for (int n = 0; n < 2; ++n) acc[m][n] = (f16v)0.f;

    // A staging: thread -> row t>>2 (0..63), granule t&3 (8 floats)
    const int rowA  = t >> 2;
    const int gA    = t & 3;
    const float* xg = X + (size_t)(m0 + rowA) * DDIM + kbeg + gA * 8;
    const int slotA = (gA ^ ((rowA >> 2) & 3)) * 8;   // validated swizzle

    const _Float16* bbase = Bp + lane * 8;

    float4 va0, va1;

#define LOADA(kb)                                                             \
    {                                                                         \
        va0 = *(const float4*)(xg + (kb));                                    \
        va1 = *(const float4*)(xg + (kb) + 4);                                \
    }

#define WRITEA(buf)                                                           \
    {                                                                         \
        h8 p0, p1;                                                            \
        const float xv[8] = {va0.x, va0.y, va0.z, va0.w,                      \
                             va1.x, va1.y, va1.z, va1.w};                     \
        _Pragma("unroll")                                                     \
        for (int q = 0; q < 8; ++q) {                                         \
            const _Float16 h0 = (_Float16)xv[q];                              \
            p0[q] = h0;                                                       \
            p1[q] = (_Float16)((xv[q] - (float)h0) * 2048.f);                 \
        }                                                                     \
        *(h8*)&sA[buf][0][rowA][slotA] = p0;                                  \
        *(h8*)&sA[buf][1][rowA][slotA] = p1;                                  \
    }

    // RB[p][n][kf]
#define BLOAD(RB, TI)                                                         \
    {                                                                         \
        _Pragma("unroll")                                                     \
        for (int p = 0; p < 2; ++p)                                           \
        _Pragma("unroll")                                                     \
        for (int n = 0; n < 2; ++n)                                           \
        _Pragma("unroll")                                                     \
        for (int kf = 0; kf < 2; ++kf)                                        \
            RB[p][n][kf] = *(const h8*)(bbase +                               \
                (((size_t)(p * 8 + w * 2 + n) * KT + ktg0 + (TI)) * 2 + kf) * 512); \
    }

#define AREAD(CUR)                                                            \
    {                                                                         \
        _Pragma("unroll")                                                     \
        for (int m = 0; m < 2; ++m)                                           \
        _Pragma("unroll")                                                     \
        for (int kf = 0; kf < 2; ++kf) {                                      \
            const int rr = m * 32 + (lane & 31);                              \
            const int sl = (((lane >> 5) + 2 * kf) ^ ((rr >> 2) & 3)) * 8;    \
            a0[m][kf] = *(const h8*)&sA[CUR][0][rr][sl];                      \
            a1[m][kf] = *(const h8*)&sA[CUR][1][rr][sl];                      \
        }                                                                     \
    }

#define MFMA3(RB)                                                             \
    {                                                                         \
        __builtin_amdgcn_s_setprio(1);                                        \
        _Pragma("unroll")                                                     \
        for (int m = 0; m < 2; ++m)                                           \
        _Pragma("unroll")                                                     \
        for (int n = 0; n < 2; ++n)                                           \
        _Pragma("unroll")                                                     \
        for (int kf = 0; kf < 2; ++kf)                                        \
            acc[m][n] = __builtin_amdgcn_mfma_f32_32x32x16_f16(               \
                a0[m][kf], RB[0][n][kf], acc[m][n], 0, 0, 0);                 \
        _Pragma("unroll")                                                     \
        for (int n = 0; n < 2; ++n)                                           \
        _Pragma("unroll")                                                     \
        for (int kf = 0; kf < 2; ++kf)                                        \
        _Pragma("unroll")                                                     \
        for (int q = 0; q < 8; ++q) RB[0][n][kf][q] *= S5;                    \
        _Pragma("unroll")                                                     \
        for (int m = 0; m < 2; ++m)                                           \
        _Pragma("unroll")                                                     \
        for (int kf = 0; kf < 2; ++kf)                                        \
        _Pragma("unroll")                                                     \
        for (int q = 0; q < 8; ++q) a1[m][kf][q] *= S6;                       \
        _Pragma("unroll")                                                     \
        for (int m = 0; m < 2; ++m)                                           \
        _Pragma("unroll")                                                     \
        for (int n = 0; n < 2; ++n)                                           \
        _Pragma("unroll")                                                     \
        for (int kf = 0; kf < 2; ++kf)                                        \
            acc[m][n] = __builtin_amdgcn_mfma_f32_32x32x16_f16(               \
                a1[m][kf], RB[0][n][kf], acc[m][n], 0, 0, 0);                 \
        _Pragma("unroll")                                                     \
        for (int m = 0; m < 2; ++m)                                           \
        _Pragma("unroll")                                                     \
        for (int kf = 0; kf < 2; ++kf)                                        \
        _Pragma("unroll")                                                     \
        for (int q = 0; q < 8; ++q) a0[m][kf][q] *= S5;                       \
        _Pragma("unroll")                                                     \
        for (int m = 0; m < 2; ++m)                                           \
        _Pragma("unroll")                                                     \
        for (int n = 0; n < 2; ++n)                                           \
        _Pragma("unroll")                                                     \
        for (int kf = 0; kf < 2; ++kf)                                        \
            acc[m][n] = __builtin_amdgcn_mfma_f32_32x32x16_f16(               \
                a0[m][kf], RB[1][n][kf], acc[m][n], 0, 0, 0);                 \
        __builtin_amdgcn_s_setprio(0);                                        \
    }

    const _Float16 S5 = (_Float16)0.03125f;     // 2^-5
    const _Float16 S6 = (_Float16)0.015625f;    // 2^-6

    h8 bE[2][2][2], bO[2][2][2];

    // ---- prologue: A(0)->buf0; B(0)->E ----
    LOADA(0);
    BLOAD(bE, 0);
    WRITEA(0);
    asm volatile("s_waitcnt lgkmcnt(0)" ::: "memory");
    __builtin_amdgcn_s_barrier();

    for (int ti = 0; ti < nt; ti += 2) {
        {   // even: tile ti from sA[0], bE
            h8 a0[2][2], a1[2][2];
            const bool hn = (ti + 1) < nt;
            if (hn) { LOADA((ti + 1) * 32); BLOAD(bO, ti + 1); }
            AREAD(0);
            MFMA3(bE);
            if (hn) WRITEA(1);
            asm volatile("s_waitcnt lgkmcnt(0)" ::: "memory");
            __builtin_amdgcn_s_barrier();
        }
        {   // odd: tile ti+1 from sA[1], bO
            h8 a0[2][2], a1[2][2];
            const bool hn = (ti + 2) < nt;
            if (hn) { LOADA((ti + 2) * 32); BLOAD(bE, ti + 2); }
            if (ti + 1 < nt) {
                AREAD(1);
                MFMA3(bO);
            }
            if (hn) WRITEA(0);
            asm volatile("s_waitcnt lgkmcnt(0)" ::: "memory");
            __builtin_amdgcn_s_barrier();
        }
    }

    // epilogue: logit = acc/256; C/D col=lane&31, row=(r&3)+8*(r>>2)+4*(lane>>5)
    const float s0 = 1.f / 256.f;
#pragma unroll
    for (int m = 0; m < 2; ++m)
#pragma unroll
        for (int n = 0; n < 2; ++n)
#pragma unroll
            for (int r = 0; r < 16; ++r) {
                const int row = (r & 3) + 8 * (r >> 2) + 4 * (lane >> 5);
                const int gr  = m0 + m * 32 + row;
                const int gc  = w * 64 + n * 32 + (lane & 31);
                P[((size_t)ks * TDIM + gr) * EDIM + gc] = acc[m][n][r] * s0;
            }
}

// ---------------- K3: reduce + sigmoid + grouped top-k route ----------------
__global__ __launch_bounds__(256, 4)
void route_kernel(const float* __restrict__ P,
                  const float* __restrict__ B,
                  float* __restrict__ out,
                  int splitK)
{
    const int t    = threadIdx.x;
    const int lane = t & 63;
    const int wid  = t >> 6;
    const int tok0 = blockIdx.x * 32 + wid * 8;

    const float4 bv4 = *(const float4*)&B[lane * 4];
    const float bb[4] = {bv4.x, bv4.y, bv4.z, bv4.w};
    const int g = lane >> 3;

#pragma unroll
    for (int i = 0; i < 8; ++i) {
        const int tok = tok0 + i;
        float a[4] = {0.f, 0.f, 0.f, 0.f};
        for (int ksl = 0; ksl < splitK; ++ksl) {
            const float4 pv =
                *(const float4*)&P[((size_t)ksl * TDIM + tok) * EDIM + lane * 4];
            a[0] += pv.x; a[1] += pv.y; a[2] += pv.z; a[3] += pv.w;
        }
        float v[4], s[4];
#pragma unroll
        for (int jq = 0; jq < 4; ++jq) {
            v[jq] = 1.f / (1.f + expf(-a[jq]));
            s[jq] = v[jq] + bb[jq];
        }
        float t1 = s[0], t2 = -FLT_MAX;
#pragma unroll
        for (int jq = 1; jq < 4; ++jq) {
            if (s[jq] > t1) { t2 = t1; t1 = s[jq]; }
            else if (s[jq] > t2) t2 = s[jq];
        }
#pragma unroll
        for (int d = 1; d < 8; d <<= 1) {
            float o1 = __shfl_xor(t1, d);
            float o2 = __shfl_xor(t2, d);
            float n1 = fmaxf(t1, o1);
            float n2 = fmaxf(fminf(t1, o1), fmaxf(t2, o2));
            t1 = n1; t2 = n2;
        }
        const float gsc = t1 + t2;
        float gs[8];
#pragma unroll
        for (int q = 0; q < 8; ++q) gs[q] = __shfl(gsc, q * 8);
        int gmask = 0;
#pragma unroll
        for (int it = 0; it < 4; ++it) {
            float bvv = -FLT_MAX; int bg = 0;
#pragma unroll
            for (int q = 0; q < 8; ++q) {
                const bool avail = ((gmask >> q) & 1) == 0;
                if (avail && gs[q] > bvv) { bvv = gs[q]; bg = q; }
            }
            gmask |= (1 << bg);
        }
        if (((gmask >> g) & 1) == 0) { s[0] = 0.f; s[1] = 0.f; s[2] = 0.f; s[3] = 0.f; }

        float wk[8]; int ik[8]; float wsum = 0.f;
#pragma unroll
        for (int it = 0; it < 8; ++it) {
            float bvv = s[0]; int bi = lane * 4; float bs = v[0];
#pragma unroll
            for (int jq = 1; jq < 4; ++jq)
                if (s[jq] > bvv) { bvv = s[jq]; bi = lane * 4 + jq; bs = v[jq]; }
#pragma unroll
            for (int d = 1; d < 64; d <<= 1) {
                float ov = __shfl_xor(bvv, d);
                int   oi = __shfl_xor(bi, d);
                float os = __shfl_xor(bs, d);
                if (ov > bvv || (ov == bvv && oi < bi)) { bvv = ov; bi = oi; bs = os; }
            }
            wk[it] = bs; ik[it] = bi; wsum += bs;
#pragma unroll
            for (int jq = 0; jq < 4; ++jq)
                if (bi == lane * 4 + jq) s[jq] = -FLT_MAX;
        }
        const float den = wsum + 1e-20f;
        if (lane == 0) {
#pragma unroll
            for (int q = 0; q < 8; ++q) {
                out[(size_t)tok * 8 + q] = wk[q] / den * 2.5f;
                out[(size_t)TDIM * 8 + (size_t)tok * 8 + q] = (float)ik[q];
            }
        }
    }
}

extern "C" void kernel_launch(void* const* d_in, const int* in_sizes, int n_in,
                              void* d_out, int out_size, void* d_ws, size_t ws_size,
                              hipStream_t stream)
{
    (void)in_sizes; (void)n_in; (void)out_size; (void)ws_size;
    const float* x    = (const float*)d_in[0];
    const float* kern = (const float*)d_in[1];
    const float* bias = (const float*)d_in[2];
    float* out = (float*)d_out;

    float* P = (float*)d_ws;                                     // 6x8MB = 50.3MB
    _Float16* Bp = (_Float16*)((char*)d_ws +
                               (size_t)SPLITK * TDIM * EDIM * 4);

    convert_w<<<dim3(DDIM / 64, EDIM / 64), 256, 0, stream>>>(kern, Bp);
    gemm_mfma<<<(TDIM / 64) * SPLITK, 256, 0, stream>>>(x, Bp, P);
    route_kernel<<<TDIM / 32, 256, 0, stream>>>(P, bias, out, SPLITK);
}

// Round 20
// 161.795 us; speedup vs baseline: 1.5491x; 1.1467x over previous
//
#include <hip/hip_runtime.h>
#include <math.h>
#include <float.h>

// DeepSeek V3 router, round 20 = R13 restored verbatim (best measured:
// 162.07 us total). R14-R19 explored FIFO decoupling, scale-free bf16
// numerics, 128x128 tiles, splitK=6 occupancy — all neutral or worse.
// R13: 4-phase-per-K64 schedule (T3/T4/T5 port), block 64Mx256N, 4 waves,
// wave-tile 64x64, A via XOR-swizzled LDS (2-deep X staging), B global->reg
// from fragment-packed L2-resident planes, splitK=4, grid 512.
// Numerics (validated R7-R19): pass1 a0*b0; b0*=S5; a1*=S6; pass2 a1*b0s;
// a0*=S5; pass3 a0s*b3; a0=fp16(x), a1=fp16(res_x*2048), b0=fp16(256w),
// b3=fp16(res_w256*32); logit = acc/256.

#define TDIM 8192
#define DDIM 7168
#define EDIM 256
#define KT   (DDIM / 32)   // 224 k-tiles of 32

typedef _Float16 h8 __attribute__((ext_vector_type(8)));
typedef float  f16v __attribute__((ext_vector_type(16)));

// ---------------- K1: W -> 32x32x16-fragment-packed fp16 planes ------------
__global__ __launch_bounds__(256)
void convert_w(const float* __restrict__ W, _Float16* __restrict__ Bp)
{
    __shared__ _Float16 l0[64][80];
    __shared__ _Float16 l1[64][80];
    const int t = threadIdx.x;
    const int kt = blockIdx.x * 64;
    const int et = blockIdx.y * 64;
#pragma unroll
    for (int i = 0; i < 16; ++i) {
        const int kr = (t >> 6) * 16 + i;
        const int ec = t & 63;
        const float w = W[(size_t)(kt + kr) * EDIM + et + ec] * 256.f;
        const _Float16 h0 = (_Float16)w;
        const _Float16 h1 = (_Float16)((w - (float)h0) * 32.f);
        l0[ec][kr] = h0;
        l1[ec][kr] = h1;
    }
    __syncthreads();
#pragma unroll
    for (int j = 0; j < 2; ++j) {
        const int er = t >> 2;
        const int kc = ((t & 3) + 4 * j) * 8;
        const int e  = et + er;
        const int k  = kt + kc;
        const int cf   = e >> 5;
        const int lane = (e & 31) + 32 * ((k >> 3) & 1);
        const int kf   = (k >> 4) & 1;
        const int ktl  = k >> 5;
        const uint4 v0 = *(const uint4*)&l0[er][kc];
        const uint4 v1 = *(const uint4*)&l1[er][kc];
        const size_t o0 = (((size_t)(0 * 8 + cf) * KT + ktl) * 2 + kf) * 512 + lane * 8;
        const size_t o1 = (((size_t)(1 * 8 + cf) * KT + ktl) * 2 + kf) * 512 + lane * 8;
        *(uint4*)&Bp[o0] = v0;
        *(uint4*)&Bp[o1] = v1;
    }
}

// ---- K2: 4-phase-per-K64 split-fp16 GEMM (A LDS-swizzled, B from L2) ------
__global__ __launch_bounds__(256, 2)
void gemm_mfma(const float* __restrict__ X,
               const _Float16* __restrict__ Bp,
               float* __restrict__ P,
               int splitK, int kLen)
{
    __shared__ _Float16 sA[2][2][64][64];   // [buf][plane][row][halfs], 64 KB

    const int t    = threadIdx.x;
    const int lane = t & 63;
    const int w    = t >> 6;                // wave -> n-quadrant w*64

    const int bid  = blockIdx.x;
    const int ks   = (bid & 7) % splitK;
    const int mb   = (bid >> 3) * (8 / splitK) + (bid & 7) / splitK;
    const int m0   = mb * 64;
    const int kbeg = ks * kLen;
    const int nsteps = kLen >> 6;           // 28 (even)
    const int k16b   = kbeg >> 4;

    f16v acc[2][2];
#pragma unroll
    for (int m = 0; m < 2; ++m)
#pragma unroll
        for (int n = 0; n < 2; ++n) acc[m][n] = (f16v)0.f;

    // X staging: thread -> row srow(+32/piece), 8 floats at scol (256B/8 lanes)
    const int srow = t >> 3;                // 0..31
    const int sg   = t & 7;                 // raw 16B granule
    const float* xg = X + (size_t)(m0 + srow) * DDIM + kbeg + sg * 8;

    const _Float16* bb = Bp + lane * 8;

    const _Float16 S5 = (_Float16)0.03125f;     // 2^-5
    const _Float16 S6 = (_Float16)0.015625f;    // 2^-6

#define AREAD(CUR, Q)                                                         \
    {                                                                         \
        _Pragma("unroll")                                                     \
        for (int m = 0; m < 2; ++m) {                                         \
            const int rr = m * 32 + (lane & 31);                              \
            const int gq = ((((Q) * 2 + (lane >> 5)) ^ (rr & 7))) * 8;        \
            a0[m] = *(const h8*)&sA[CUR][0][rr][gq];                          \
            a1[m] = *(const h8*)&sA[CUR][1][rr][gq];                          \
        }                                                                     \
    }

#define BLOADQ(RB, K16)                                                       \
    {                                                                         \
        _Pragma("unroll")                                                     \
        for (int p = 0; p < 2; ++p)                                           \
        _Pragma("unroll")                                                     \
        for (int n = 0; n < 2; ++n)                                           \
            RB[n][p] = *(const h8*)(bb +                                      \
                ((size_t)(p * 8 + w * 2 + n) * (2 * KT) + (K16)) * 512);      \
    }

#define LOADX2(R0, R1, PIECE, S)                                              \
    {                                                                         \
        const float* xp = xg + (size_t)(PIECE) * 32 * DDIM + (S) * 64;        \
        R0 = *(const float4*)(xp);                                            \
        R1 = *(const float4*)(xp + 4);                                        \
    }

#define CONVW(BUF, PIECE, R0, R1)                                             \
    {                                                                         \
        h8 p0, p1;                                                            \
        const float xv[8] = {R0.x, R0.y, R0.z, R0.w, R1.x, R1.y, R1.z, R1.w}; \
        _Pragma("unroll")                                                     \
        for (int q = 0; q < 8; ++q) {                                         \
            const _Float16 h0 = (_Float16)xv[q];                              \
            p0[q] = h0;                                                       \
            p1[q] = (_Float16)((xv[q] - (float)h0) * 2048.f);                 \
        }                                                                     \
        const int r  = srow + 32 * (PIECE);                                   \
        const int gq = (sg ^ (r & 7)) * 8;                                    \
        *(h8*)&sA[BUF][0][r][gq] = p0;                                        \
        *(h8*)&sA[BUF][1][r][gq] = p1;                                        \
    }

#define MFMAQ(RB)                                                             \
    {                                                                         \
        __builtin_amdgcn_s_setprio(1);                                        \
        _Pragma("unroll")                                                     \
        for (int m = 0; m < 2; ++m)                                           \
        _Pragma("unroll")                                                     \
        for (int n = 0; n < 2; ++n)                                           \
            acc[m][n] = __builtin_amdgcn_mfma_f32_32x32x16_f16(               \
                a0[m], RB[n][0], acc[m][n], 0, 0, 0);                         \
        _Pragma("unroll")                                                     \
        for (int n = 0; n < 2; ++n)                                           \
        _Pragma("unroll")                                                     \
        for (int q = 0; q < 8; ++q) RB[n][0][q] *= S5;                        \
        _Pragma("unroll")                                                     \
        for (int m = 0; m < 2; ++m)                                           \
        _Pragma("unroll")                                                     \
        for (int q = 0; q < 8; ++q) a1[m][q] *= S6;                           \
        _Pragma("unroll")                                                     \
        for (int m = 0; m < 2; ++m)                                           \
        _Pragma("unroll")                                                     \
        for (int n = 0; n < 2; ++n)                                           \
            acc[m][n] = __builtin_amdgcn_mfma_f32_32x32x16_f16(               \
                a1[m], RB[n][0], acc[m][n], 0, 0, 0);                         \
        _Pragma("unroll")                                                     \
        for (int m = 0; m < 2; ++m)                                           \
        _Pragma("unroll")                                                     \
        for (int q = 0; q < 8; ++q) a0[m][q] *= S5;                           \
        _Pragma("unroll")                                                     \
        for (int m = 0; m < 2; ++m)                                           \
        _Pragma("unroll")                                                     \
        for (int n = 0; n < 2; ++n)                                           \
            acc[m][n] = __builtin_amdgcn_mfma_f32_32x32x16_f16(               \
                a0[m], RB[n][1], acc[m][n], 0, 0, 0);                         \
        __builtin_amdgcn_s_setprio(0);                                        \
    }

#define PHASE(CUR, Q, RB, STG, BNX)                                           \
    {                                                                         \
        h8 a0[2], a1[2];                                                      \
        AREAD(CUR, Q);                                                        \
        STG;                                                                  \
        __builtin_amdgcn_s_barrier();                                         \
        asm volatile("s_waitcnt lgkmcnt(0)" ::: "memory");                    \
        __builtin_amdgcn_sched_barrier(0);                                    \
        MFMAQ(RB);                                                            \
        BNX;                                                                  \
        __builtin_amdgcn_s_barrier();                                         \
    }

#define STEP_BODY(S, CUR, L0, L1, L2, L3, W0, W1, W2, W3)                     \
    {                                                                         \
        const int kk = k16b + (S) * 4;                                        \
        const bool h1 = (S) + 1 < nsteps;                                     \
        const bool h2 = (S) + 2 < nsteps;                                     \
        PHASE(CUR, 0, bBuf0,                                                  \
              { if (h2) LOADX2(L0, L1, 0, (S) + 2); },                        \
              { BLOADQ(bBuf0, kk + 2); });                                    \
        PHASE(CUR, 1, bBuf1,                                                  \
              { if (h1) CONVW((CUR) ^ 1, 0, W0, W1); },                       \
              { BLOADQ(bBuf1, kk + 3); });                                    \
        PHASE(CUR, 2, bBuf0,                                                  \
              { if (h2) LOADX2(L2, L3, 1, (S) + 2); },                        \
              { if (h1) BLOADQ(bBuf0, kk + 4); });                            \
        PHASE(CUR, 3, bBuf1,                                                  \
              { if (h1) CONVW((CUR) ^ 1, 1, W2, W3); },                       \
              { if (h1) BLOADQ(bBuf1, kk + 5); });                            \
    }

    float4 xA0, xA1, xA2, xA3, xB0, xB1, xB2, xB3;
    h8 bBuf0[2][2], bBuf1[2][2];

    // ---- prologue ----
    LOADX2(xA0, xA1, 0, 0);
    LOADX2(xA2, xA3, 1, 0);
    BLOADQ(bBuf0, k16b + 0);
    BLOADQ(bBuf1, k16b + 1);
    CONVW(0, 0, xA0, xA1);
    CONVW(0, 1, xA2, xA3);
    if (nsteps > 1) { LOADX2(xB0, xB1, 0, 1); LOADX2(xB2, xB3, 1, 1); }
    asm volatile("s_waitcnt lgkmcnt(0)" ::: "memory");
    __builtin_amdgcn_s_barrier();

    for (int s = 0; s < nsteps; s += 2) {
        STEP_BODY(s,     0, xA0, xA1, xA2, xA3, xB0, xB1, xB2, xB3);
        STEP_BODY(s + 1, 1, xB0, xB1, xB2, xB3, xA0, xA1, xA2, xA3);
    }

    // epilogue: logit = acc/256; C/D col=lane&31, row=(r&3)+8*(r>>2)+4*(lane>>5)
    const float s0 = 1.f / 256.f;
#pragma unroll
    for (int m = 0; m < 2; ++m)
#pragma unroll
        for (int n = 0; n < 2; ++n)
#pragma unroll
            for (int r = 0; r < 16; ++r) {
                const int row = (r & 3) + 8 * (r >> 2) + 4 * (lane >> 5);
                const int gr  = m0 + m * 32 + row;
                const int gc  = w * 64 + n * 32 + (lane & 31);
                P[((size_t)ks * TDIM + gr) * EDIM + gc] = acc[m][n][r] * s0;
            }
}

// ---------------- K3: reduce + sigmoid + grouped top-k route ----------------
__global__ __launch_bounds__(256, 4)
void route_kernel(const float* __restrict__ P,
                  const float* __restrict__ B,
                  float* __restrict__ out,
                  int splitK)
{
    const int t    = threadIdx.x;
    const int lane = t & 63;
    const int wid  = t >> 6;
    const int tok0 = blockIdx.x * 32 + wid * 8;

    const float4 bv4 = *(const float4*)&B[lane * 4];
    const float bb[4] = {bv4.x, bv4.y, bv4.z, bv4.w};
    const int g = lane >> 3;

#pragma unroll
    for (int i = 0; i < 8; ++i) {
        const int tok = tok0 + i;
        float a[4] = {0.f, 0.f, 0.f, 0.f};
        for (int ksl = 0; ksl < splitK; ++ksl) {
            const float4 pv =
                *(const float4*)&P[((size_t)ksl * TDIM + tok) * EDIM + lane * 4];
            a[0] += pv.x; a[1] += pv.y; a[2] += pv.z; a[3] += pv.w;
        }
        float v[4], s[4];
#pragma unroll
        for (int jq = 0; jq < 4; ++jq) {
            v[jq] = 1.f / (1.f + expf(-a[jq]));
            s[jq] = v[jq] + bb[jq];
        }
        float t1 = s[0], t2 = -FLT_MAX;
#pragma unroll
        for (int jq = 1; jq < 4; ++jq) {
            if (s[jq] > t1) { t2 = t1; t1 = s[jq]; }
            else if (s[jq] > t2) t2 = s[jq];
        }
#pragma unroll
        for (int d = 1; d < 8; d <<= 1) {
            float o1 = __shfl_xor(t1, d);
            float o2 = __shfl_xor(t2, d);
            float n1 = fmaxf(t1, o1);
            float n2 = fmaxf(fminf(t1, o1), fmaxf(t2, o2));
            t1 = n1; t2 = n2;
        }
        const float gsc = t1 + t2;
        float gs[8];
#pragma unroll
        for (int q = 0; q < 8; ++q) gs[q] = __shfl(gsc, q * 8);
        int gmask = 0;
#pragma unroll
        for (int it = 0; it < 4; ++it) {
            float bvv = -FLT_MAX; int bg = 0;
#pragma unroll
            for (int q = 0; q < 8; ++q) {
                const bool avail = ((gmask >> q) & 1) == 0;
                if (avail && gs[q] > bvv) { bvv = gs[q]; bg = q; }
            }
            gmask |= (1 << bg);
        }
        if (((gmask >> g) & 1) == 0) { s[0] = 0.f; s[1] = 0.f; s[2] = 0.f; s[3] = 0.f; }

        float wk[8]; int ik[8]; float wsum = 0.f;
#pragma unroll
        for (int it = 0; it < 8; ++it) {
            float bvv = s[0]; int bi = lane * 4; float bs = v[0];
#pragma unroll
            for (int jq = 1; jq < 4; ++jq)
                if (s[jq] > bvv) { bvv = s[jq]; bi = lane * 4 + jq; bs = v[jq]; }
#pragma unroll
            for (int d = 1; d < 64; d <<= 1) {
                float ov = __shfl_xor(bvv, d);
                int   oi = __shfl_xor(bi, d);
                float os = __shfl_xor(bs, d);
                if (ov > bvv || (ov == bvv && oi < bi)) { bvv = ov; bi = oi; bs = os; }
            }
            wk[it] = bs; ik[it] = bi; wsum += bs;
#pragma unroll
            for (int jq = 0; jq < 4; ++jq)
                if (bi == lane * 4 + jq) s[jq] = -FLT_MAX;
        }
        const float den = wsum + 1e-20f;
        if (lane == 0) {
#pragma unroll
            for (int q = 0; q < 8; ++q) {
                out[(size_t)tok * 8 + q] = wk[q] / den * 2.5f;
                out[(size_t)TDIM * 8 + (size_t)tok * 8 + q] = (float)ik[q];
            }
        }
    }
}

extern "C" void kernel_launch(void* const* d_in, const int* in_sizes, int n_in,
                              void* d_out, int out_size, void* d_ws, size_t ws_size,
                              hipStream_t stream)
{
    (void)in_sizes; (void)n_in; (void)out_size;
    const float* x    = (const float*)d_in[0];
    const float* kern = (const float*)d_in[1];
    const float* bias = (const float*)d_in[2];
    float* out = (float*)d_out;

    const size_t packedBytes = (size_t)2 * 8 * KT * 2 * 512 * 2;   // 7.34 MB
    int splitK = 4;
    while (splitK > 1 &&
           (size_t)splitK * TDIM * EDIM * 4 + packedBytes > ws_size)
        splitK >>= 1;

    float* P = (float*)d_ws;
    _Float16* Bp = (_Float16*)((char*)d_ws + (size_t)splitK * TDIM * EDIM * 4);

    convert_w<<<dim3(DDIM / 64, EDIM / 64), 256, 0, stream>>>(kern, Bp);
    gemm_mfma<<<(TDIM / 64) * splitK, 256, 0, stream>>>(
        x, Bp, P, splitK, DDIM / splitK);
    route_kernel<<<TDIM / 32, 256, 0, stream>>>(P, bias, out, splitK);
}